// Round 6
// baseline (12983.865 us; speedup 1.0000x reference)
//
#include <hip/hip_runtime.h>
#include <math.h>

// 2-layer LSTM, B=32 T=256 D=512 H=1024, gate order i,j,f,o, forget bias 1.0
// 5 dispatches: sgemm(ZX1p) -> lstm_seq(L1) -> sgemm(ZX2p) -> lstm_seq(L2)
// lstm_seq v3: Wh slice LDS-resident (64KB/block, loaded once), no k-split.
//   Block jb (0..255) owns 16 cols {jb*4+jj + 1024*g}. Thread tid:
//   b = tid>>4, c = tid&15, g = c>>2, jj = c&3  -> ONE output (b, jb*4+jj).
//   Dot: 1024 FMAs over LDS-Wh (bank-safe stride 1028) x global h (L1/L2).
//   Gate combine: 3x shfl_xor over g-lanes; c state in registers.
//   ZX is written PERMUTED by the GEMM epilogue: [t][jb][b*16+c] so each
//   block reads one contiguous 2KB chunk per step.

#define HSZ 1024
#define GSZ 4096
#define TSZ 256
#define BSZ 32
#define DSZ 512

__device__ __forceinline__ float sigf(float x) { return 1.0f / (1.0f + __expf(-x)); }

// ---------------- fp32 SGEMM: C = A[M,K] @ Bm[K,N], C written ZX-permuted ----
// BM=BN=128, BK=16, 256 threads, 8x8 per thread.
__global__ __launch_bounds__(256)
void sgemm128p(const float* __restrict__ A, const float* __restrict__ Bm,
               float* __restrict__ ZXp, int M, int N, int K) {
  __shared__ float As[16][132];
  __shared__ float Bs[16][132];
  const int tid = threadIdx.x;
  const int m_base = blockIdx.y * 128;
  const int n_base = blockIdx.x * 128;
  const int tm = tid >> 4, tn = tid & 15;
  float acc[8][8];
#pragma unroll
  for (int i = 0; i < 8; ++i)
#pragma unroll
    for (int j = 0; j < 8; ++j) acc[i][j] = 0.0f;

  for (int kt = 0; kt < K; kt += 16) {
#pragma unroll
    for (int i = 0; i < 2; ++i) {
      int q = tid * 2 + i;
      int ar = q >> 2, akq = (q & 3) * 4;
      float4 av = *(const float4*)(A + (size_t)(m_base + ar) * K + kt + akq);
      As[akq + 0][ar] = av.x;
      As[akq + 1][ar] = av.y;
      As[akq + 2][ar] = av.z;
      As[akq + 3][ar] = av.w;
      int bk = q >> 5, bnq = (q & 31) * 4;
      *(float4*)&Bs[bk][bnq] =
          *(const float4*)(Bm + (size_t)(kt + bk) * N + n_base + bnq);
    }
    __syncthreads();
#pragma unroll
    for (int k = 0; k < 16; ++k) {
      float a[8], b[8];
      *(float4*)&a[0] = *(const float4*)&As[k][tm * 8];
      *(float4*)&a[4] = *(const float4*)&As[k][tm * 8 + 4];
      *(float4*)&b[0] = *(const float4*)&Bs[k][tn * 8];
      *(float4*)&b[4] = *(const float4*)&Bs[k][tn * 8 + 4];
#pragma unroll
      for (int i = 0; i < 8; ++i)
#pragma unroll
        for (int j = 0; j < 8; ++j) acc[i][j] = fmaf(a[i], b[j], acc[i][j]);
    }
    __syncthreads();
  }
  // Epilogue: permuted store. ZXp[t][jb][b*16 + c], c = g*4+jj, 512 floats/(t,jb).
  const int g = n_base >> 10;  // gate, uniform per block (1024 % 128 == 0)
#pragma unroll
  for (int i = 0; i < 8; ++i) {
    int m = m_base + tm * 8 + i;
    int bb = m >> 8;          // b  (m = b*T + t, T=256)
    int tt = m & 255;         // t
    int n0 = n_base + tn * 8;
    int jb0 = (n0 & 1023) >> 2;
    float* p = ZXp + ((size_t)tt * 256 + jb0) * 512 + bb * 16 + g * 4;
    *(float4*)p = make_float4(acc[i][0], acc[i][1], acc[i][2], acc[i][3]);
    *(float4*)(p + 512) = make_float4(acc[i][4], acc[i][5], acc[i][6], acc[i][7]);
  }
}

// ---------------- persistent recurrent kernel (Wh in LDS) ----------------
__global__ __launch_bounds__(512, 1)
void lstm_seq(const float* __restrict__ Wh,    // [1024][4096] recurrent slice
              const float* __restrict__ ZXp,   // [T][256][512] permuted
              const float* __restrict__ bias,  // [4096]
              float* __restrict__ Hbuf,        // [B][T][1024]  (in+out)
              unsigned int* __restrict__ bar) {
  __shared__ float lds_w[16][1028];  // WhT: [c][k], stride 1028 -> 2-way banks

  const int tid = threadIdx.x;
  const int jb = blockIdx.x;        // 0..255
  const int brow = tid >> 4;        // 0..31
  const int c = tid & 15;           // g*4 + jj
  const int g = c >> 2;
  const int jj = c & 3;
  const int jout = jb * 4 + jj;     // output column 0..1023

  unsigned int* grpc = bar + (blockIdx.x >> 5) * 16;  // 8 group counters
  unsigned int* rootc = bar + 8 * 16;
  unsigned int* flag = bar + 9 * 16;

  // ---- stage Wh slice into LDS (once): WhT[c][k] = Wh[k][jb*4 + jj + g*1024]
#pragma unroll
  for (int i = 0; i < 32; ++i) {
    int f = i * 512 + tid;          // 0..16383
    int k = f >> 4, cc = f & 15;
    int col = jb * 4 + (cc & 3) + ((cc >> 2) << 10);
    lds_w[cc][k] = Wh[(size_t)k * GSZ + col];
  }
  const float breg = bias[jout + (g << 10)];  // bias for own col
  float creg = 0.0f;                          // c state (dup across g-lanes)
  const float* wrow = &lds_w[c][0];
  __syncthreads();

  for (int t = 0; t < TSZ; ++t) {
    float a0 = 0.f, a1 = 0.f, a2 = 0.f, a3 = 0.f;
    if (t > 0) {
      const float* hrow =
          Hbuf + (size_t)brow * (TSZ * HSZ) + (size_t)(t - 1) * HSZ;
#pragma unroll 4
      for (int kq = 0; kq < 256; ++kq) {
        float4 w4 = *(const float4*)(wrow + (kq << 2));
        float4 h4 = *(const float4*)(hrow + (kq << 2));
        a0 = fmaf(h4.x, w4.x, a0);
        a1 = fmaf(h4.y, w4.y, a1);
        a2 = fmaf(h4.z, w4.z, a2);
        a3 = fmaf(h4.w, w4.w, a3);
      }
    }
    float zx = ZXp[(size_t)t * (256 * 512) + (size_t)jb * 512 + tid];
    float z = ((a0 + a1) + (a2 + a3)) + zx + breg;

    // gate all-gather across g-lanes (lanes differ in tid bits [3:2])
    float s4 = __shfl_xor(z, 4);
    float s8 = __shfl_xor(z, 8);
    float s12 = __shfl_xor(z, 12);
    // value of gate x sits in: m = x^g: 0->z, 1->s4, 2->s8, 3->s12
    float zi = (g == 0) ? z : (g == 1) ? s4 : (g == 2) ? s8 : s12;
    float zj = (g == 1) ? z : (g == 0) ? s4 : (g == 3) ? s8 : s12;
    float zf = (g == 2) ? z : (g == 3) ? s4 : (g == 0) ? s8 : s12;
    float zo = (g == 3) ? z : (g == 2) ? s4 : (g == 1) ? s8 : s12;

    float cn = sigf(zf + 1.0f) * creg + sigf(zi) * tanhf(zj);
    float hn = sigf(zo) * tanhf(cn);
    creg = cn;

    if (g == 0) {
      // write-through to coherence point (visible to all XCDs next step)
      __hip_atomic_store(
          Hbuf + (size_t)brow * (TSZ * HSZ) + (size_t)t * HSZ + jout, hn,
          __ATOMIC_RELAXED, __HIP_MEMORY_SCOPE_AGENT);
    }
    __syncthreads();  // drains h stores (vmcnt(0) before s_barrier)

    // hierarchical grid barrier (gen = t+1), counters zeroed per launch
    if (tid == 0) {
      asm volatile("" ::: "memory");
      unsigned int old = __hip_atomic_fetch_add(grpc, 1u, __ATOMIC_RELAXED,
                                                __HIP_MEMORY_SCOPE_AGENT);
      if (old == (unsigned int)(32 * (t + 1) - 1)) {
        unsigned int ro = __hip_atomic_fetch_add(rootc, 1u, __ATOMIC_RELAXED,
                                                 __HIP_MEMORY_SCOPE_AGENT);
        if (ro == (unsigned int)(8 * (t + 1) - 1)) {
          __hip_atomic_store(flag, (unsigned int)(t + 1), __ATOMIC_RELAXED,
                             __HIP_MEMORY_SCOPE_AGENT);
        }
      }
      while (__hip_atomic_load(flag, __ATOMIC_RELAXED,
                               __HIP_MEMORY_SCOPE_AGENT) <
             (unsigned int)(t + 1)) {
        __builtin_amdgcn_s_sleep(1);
      }
      asm volatile("" ::: "memory");
    }
    __syncthreads();
  }
}

extern "C" void kernel_launch(void* const* d_in, const int* in_sizes, int n_in,
                              void* d_out, int out_size, void* d_ws, size_t ws_size,
                              hipStream_t stream) {
  const float* x  = (const float*)d_in[0];  // [32,256,512]
  const float* W1 = (const float*)d_in[1];  // [1536,4096]
  const float* b1 = (const float*)d_in[2];  // [4096]
  const float* W2 = (const float*)d_in[3];  // [2048,4096]
  const float* b2 = (const float*)d_in[4];  // [4096]
  float* out = (float*)d_out;               // [32,256,1024]

  unsigned int* bar1 = (unsigned int*)d_ws;        // 256 uints
  unsigned int* bar2 = bar1 + 256;                 // 256 uints
  float* H1buf = (float*)(bar2 + 256);             // [B,T,H]
  float* ZXp   = H1buf + (size_t)BSZ * TSZ * HSZ;  // [T][256][512] permuted

  hipMemsetAsync(bar1, 0, 512 * sizeof(unsigned int), stream);

  dim3 gemm_grid(GSZ / 128, (BSZ * TSZ) / 128);  // (32, 64)

  // Layer 1
  sgemm128p<<<gemm_grid, 256, 0, stream>>>(x, W1, ZXp, BSZ * TSZ, GSZ, DSZ);
  lstm_seq<<<256, 512, 0, stream>>>(W1 + (size_t)DSZ * GSZ, ZXp, b1, H1buf, bar1);

  // Layer 2
  sgemm128p<<<gemm_grid, 256, 0, stream>>>(H1buf, W2, ZXp, BSZ * TSZ, GSZ, HSZ);
  lstm_seq<<<256, 512, 0, stream>>>(W2 + (size_t)HSZ * GSZ, ZXp, b2, out, bar2);
}

// Round 7
// 5886.890 us; speedup vs baseline: 2.2056x; 2.2056x over previous
//
#include <hip/hip_runtime.h>
#include <math.h>

// 2-layer LSTM, B=32 T=256 D=512 H=1024, gate order i,j,f,o, forget bias 1.0
// 5 dispatches: sgemm(ZX1p) -> lstm_seq(L1) -> sgemm(ZX2p) -> lstm_seq(L2)
// lstm_seq v5: Wh in REGISTERS (128 VGPR/thread, loaded once), h[t-1] staged
//   to LDS each step (128KB, XOR-swizzled), wave reduce-scatter over k-slices.
//   Block jb owns 16 cols {jb*4+jj + 1024*g}. Thread (cq,bq,ks=lane):
//   8 cols x 8 b-rows x 16 k -> 1024 FMA into acc[64]; butterfly reduce gives
//   each lane one output (b_o, cl_o) with v = bitrev6(lane).

#define HSZ 1024
#define GSZ 4096
#define TSZ 256
#define BSZ 32
#define DSZ 512

__device__ __forceinline__ float sigf(float x) { return 1.0f / (1.0f + __expf(-x)); }

// ---------------- fp32 SGEMM: C = A[M,K] @ Bm[K,N], C written ZX-permuted ----
__global__ __launch_bounds__(256)
void sgemm128p(const float* __restrict__ A, const float* __restrict__ Bm,
               float* __restrict__ ZXp, int M, int N, int K) {
  __shared__ float As[16][132];
  __shared__ float Bs[16][132];
  const int tid = threadIdx.x;
  const int m_base = blockIdx.y * 128;
  const int n_base = blockIdx.x * 128;
  const int tm = tid >> 4, tn = tid & 15;
  float acc[8][8];
#pragma unroll
  for (int i = 0; i < 8; ++i)
#pragma unroll
    for (int j = 0; j < 8; ++j) acc[i][j] = 0.0f;

  for (int kt = 0; kt < K; kt += 16) {
#pragma unroll
    for (int i = 0; i < 2; ++i) {
      int q = tid * 2 + i;
      int ar = q >> 2, akq = (q & 3) * 4;
      float4 av = *(const float4*)(A + (size_t)(m_base + ar) * K + kt + akq);
      As[akq + 0][ar] = av.x;
      As[akq + 1][ar] = av.y;
      As[akq + 2][ar] = av.z;
      As[akq + 3][ar] = av.w;
      int bk = q >> 5, bnq = (q & 31) * 4;
      *(float4*)&Bs[bk][bnq] =
          *(const float4*)(Bm + (size_t)(kt + bk) * N + n_base + bnq);
    }
    __syncthreads();
#pragma unroll
    for (int k = 0; k < 16; ++k) {
      float a[8], b[8];
      *(float4*)&a[0] = *(const float4*)&As[k][tm * 8];
      *(float4*)&a[4] = *(const float4*)&As[k][tm * 8 + 4];
      *(float4*)&b[0] = *(const float4*)&Bs[k][tn * 8];
      *(float4*)&b[4] = *(const float4*)&Bs[k][tn * 8 + 4];
#pragma unroll
      for (int i = 0; i < 8; ++i)
#pragma unroll
        for (int j = 0; j < 8; ++j) acc[i][j] = fmaf(a[i], b[j], acc[i][j]);
    }
    __syncthreads();
  }
  // Epilogue: ZXp[t][jb][b*16 + g*4 + jj]
  const int g = n_base >> 10;  // uniform per block
#pragma unroll
  for (int i = 0; i < 8; ++i) {
    int m = m_base + tm * 8 + i;
    int bb = m >> 8;
    int tt = m & 255;
    int n0 = n_base + tn * 8;
    int jb0 = (n0 & 1023) >> 2;
    float* p = ZXp + ((size_t)tt * 256 + jb0) * 512 + bb * 16 + g * 4;
    *(float4*)p = make_float4(acc[i][0], acc[i][1], acc[i][2], acc[i][3]);
    *(float4*)(p + 512) = make_float4(acc[i][4], acc[i][5], acc[i][6], acc[i][7]);
  }
}

// ---------------- persistent recurrent kernel (Wh in registers) -------------
__global__ __launch_bounds__(512, 1)
void lstm_seq(const float* __restrict__ Wh,    // [1024][4096] recurrent slice
              const float* __restrict__ ZXp,   // [T][256][512] permuted
              const float* __restrict__ bias,  // [4096]
              float* __restrict__ Hbuf,        // [B][T][1024]  (in+out)
              unsigned int* __restrict__ bar) {
  __shared__ __align__(16) float hl[32 * 1024];  // h[t-1], XOR-swizzled f4 slots
  __shared__ float zl[512];
  __shared__ float cstl[128];

  const int tid = threadIdx.x;
  const int lane = tid & 63;      // ks: k-slice [lane*16, lane*16+16)
  const int bq = (tid >> 6) & 3;  // 8 b-rows: b = bq*8 + bb
  const int cq = tid >> 8;        // 8 cols: cl = cq*8 + (gg*4+jj), g = cq*2+gg
  const int jb = blockIdx.x;      // 0..255

  // owned output after reduce-scatter: v = bitrev6(lane)
  const int vown = ((lane & 1) << 5) | ((lane & 2) << 3) | ((lane & 4) << 1) |
                   ((lane & 8) >> 1) | ((lane & 16) >> 3) | ((lane & 32) >> 5);
  const int b_o = bq * 8 + (vown >> 3);
  const int cl_o = cq * 8 + (vown & 7);
  const float breg = bias[(cl_o >> 2) * 1024 + jb * 4 + (cl_o & 3)];

  // Wh -> registers: wreg[kt*2+gg] = Wh[lane*16+kt][(cq*2+gg)*1024 + jb*4 ..+3]
  float4 wreg[32];
#pragma unroll
  for (int kt = 0; kt < 16; ++kt)
#pragma unroll
    for (int gg = 0; gg < 2; ++gg)
      wreg[kt * 2 + gg] =
          *(const float4*)(Wh + (size_t)(lane * 16 + kt) * GSZ +
                           (size_t)(cq * 2 + gg) * 1024 + jb * 4);

  if (tid < 128) cstl[tid] = 0.0f;

  unsigned int* grpc = bar + (jb >> 5) * 16;  // 8 group counters, 64B apart
  unsigned int* rootc = bar + 8 * 16;
  unsigned int* flag = bar + 9 * 16;
  __syncthreads();

  for (int t = 0; t < TSZ; ++t) {
    if (t > 0) {
      // stage full h[t-1] (32 rows x 1024) into swizzled LDS, coalesced
#pragma unroll 8
      for (int i = 0; i < 16; ++i) {
        int f = i * 512 + tid;   // float4 index in [0, 8192)
        int bsr = f >> 8, q = f & 255;
        float4 v = *(const float4*)(Hbuf + (size_t)bsr * (TSZ * HSZ) +
                                    (size_t)(t - 1) * HSZ + (q << 2));
        int slot = bsr * 256 + (q ^ ((q >> 3) & 7));
        *(float4*)&hl[slot << 2] = v;
      }
      __syncthreads();
    }

    float acc[64];
#pragma unroll
    for (int i = 0; i < 64; ++i) acc[i] = 0.0f;

    if (t > 0) {
#pragma unroll
      for (int bb = 0; bb < 8; ++bb) {
        int b = bq * 8 + bb;
        float4 h4[4];
#pragma unroll
        for (int kk = 0; kk < 4; ++kk) {
          int q = lane * 4 + kk;
          int slot = b * 256 + (q ^ ((q >> 3) & 7));
          h4[kk] = *(const float4*)&hl[slot << 2];
        }
#pragma unroll
        for (int kk = 0; kk < 4; ++kk)
#pragma unroll
          for (int j = 0; j < 4; ++j) {
            float hv = (j == 0)   ? h4[kk].x
                       : (j == 1) ? h4[kk].y
                       : (j == 2) ? h4[kk].z
                                  : h4[kk].w;
            int kt = kk * 4 + j;
#pragma unroll
            for (int gg = 0; gg < 2; ++gg) {
              float4 w = wreg[kt * 2 + gg];
              int a0 = bb * 8 + gg * 4;
              acc[a0 + 0] = fmaf(hv, w.x, acc[a0 + 0]);
              acc[a0 + 1] = fmaf(hv, w.y, acc[a0 + 1]);
              acc[a0 + 2] = fmaf(hv, w.z, acc[a0 + 2]);
              acc[a0 + 3] = fmaf(hv, w.w, acc[a0 + 3]);
            }
          }
      }
    }

    // wave reduce-scatter over the 64 k-slice lanes (butterfly, value-halving)
#pragma unroll
    for (int r = 0; r < 6; ++r) {
      const int d = 1 << r;
      const int half = 32 >> r;
      const bool up = (lane >> r) & 1;
#pragma unroll
      for (int i = 0; i < half; ++i) {
        float send = up ? acc[i] : acc[i + half];
        float keep = up ? acc[i + half] : acc[i];
        float got = __shfl_xor(send, d);
        acc[i] = keep + got;
      }
    }

    // this thread owns z for (b_o, cl_o)
    zl[b_o * 16 + cl_o] =
        acc[0] + ZXp[((size_t)t * 256 + jb) * 512 + b_o * 16 + cl_o] + breg;
    __syncthreads();

    if (tid < 128) {
      int b = tid >> 2, jj = tid & 3;
      float zi = zl[b * 16 + jj];
      float zj = zl[b * 16 + 4 + jj];
      float zf = zl[b * 16 + 8 + jj];
      float zo = zl[b * 16 + 12 + jj];
      float cold = cstl[tid];
      float cn = sigf(zf + 1.0f) * cold + sigf(zi) * tanhf(zj);
      float hn = sigf(zo) * tanhf(cn);
      cstl[tid] = cn;
      __hip_atomic_store(Hbuf + (size_t)b * (TSZ * HSZ) + (size_t)t * HSZ +
                             jb * 4 + jj,
                         hn, __ATOMIC_RELAXED, __HIP_MEMORY_SCOPE_AGENT);
    }
    __syncthreads();  // drains h stores (vmcnt(0) before s_barrier)

    // hierarchical grid barrier (gen = t+1), counters zeroed per launch
    if (tid == 0) {
      asm volatile("" ::: "memory");
      unsigned int old = __hip_atomic_fetch_add(grpc, 1u, __ATOMIC_RELAXED,
                                                __HIP_MEMORY_SCOPE_AGENT);
      if (old == (unsigned int)(32 * (t + 1) - 1)) {
        unsigned int ro = __hip_atomic_fetch_add(rootc, 1u, __ATOMIC_RELAXED,
                                                 __HIP_MEMORY_SCOPE_AGENT);
        if (ro == (unsigned int)(8 * (t + 1) - 1)) {
          __hip_atomic_store(flag, (unsigned int)(t + 1), __ATOMIC_RELAXED,
                             __HIP_MEMORY_SCOPE_AGENT);
        }
      }
      while (__hip_atomic_load(flag, __ATOMIC_RELAXED,
                               __HIP_MEMORY_SCOPE_AGENT) <
             (unsigned int)(t + 1)) {
        __builtin_amdgcn_s_sleep(1);
      }
      asm volatile("" ::: "memory");
    }
    __syncthreads();
  }
}

extern "C" void kernel_launch(void* const* d_in, const int* in_sizes, int n_in,
                              void* d_out, int out_size, void* d_ws, size_t ws_size,
                              hipStream_t stream) {
  const float* x  = (const float*)d_in[0];  // [32,256,512]
  const float* W1 = (const float*)d_in[1];  // [1536,4096]
  const float* b1 = (const float*)d_in[2];  // [4096]
  const float* W2 = (const float*)d_in[3];  // [2048,4096]
  const float* b2 = (const float*)d_in[4];  // [4096]
  float* out = (float*)d_out;               // [32,256,1024]

  unsigned int* bar1 = (unsigned int*)d_ws;        // 256 uints
  unsigned int* bar2 = bar1 + 256;                 // 256 uints
  float* H1buf = (float*)(bar2 + 256);             // [B,T,H]
  float* ZXp   = H1buf + (size_t)BSZ * TSZ * HSZ;  // [T][256][512] permuted

  hipMemsetAsync(bar1, 0, 512 * sizeof(unsigned int), stream);

  dim3 gemm_grid(GSZ / 128, (BSZ * TSZ) / 128);  // (32, 64)

  // Layer 1
  sgemm128p<<<gemm_grid, 256, 0, stream>>>(x, W1, ZXp, BSZ * TSZ, GSZ, DSZ);
  lstm_seq<<<256, 512, 0, stream>>>(W1 + (size_t)DSZ * GSZ, ZXp, b1, H1buf, bar1);

  // Layer 2
  sgemm128p<<<gemm_grid, 256, 0, stream>>>(H1buf, W2, ZXp, BSZ * TSZ, GSZ, HSZ);
  lstm_seq<<<256, 512, 0, stream>>>(W2 + (size_t)HSZ * GSZ, ZXp, b2, out, bar2);
}